// Round 7
// baseline (401.449 us; speedup 1.0000x reference)
//
#include <hip/hip_runtime.h>
#include <cstdint>

typedef __attribute__((ext_vector_type(8))) short bf16x8;
typedef __attribute__((ext_vector_type(4))) float f32x4;

__device__ __forceinline__ unsigned short f2bf(float v) {
  unsigned u = __builtin_bit_cast(unsigned, v);
  u += 0x7FFFu + ((u >> 16) & 1u);   // RNE
  return (unsigned short)(u >> 16);
}

// async global->LDS, 16B per lane; LDS dest = wave-uniform base + lane*16
__device__ __forceinline__ void gload16(const unsigned short* g, unsigned short* l) {
  __builtin_amdgcn_global_load_lds(
      (const __attribute__((address_space(1))) void*)(uintptr_t)g,
      (__attribute__((address_space(3))) void*)(uint32_t)(uintptr_t)l,
      16, 0, 0);
}

// Single-pass bf16 NT GEMM core: C[128x128] += A[128xK] * B[128xK]^T, BK=64.
// (r0-proven structure: 2x __syncthreads per K-tile, 256 thr / 4 waves,
//  32 KiB LDS -> TLP from co-resident blocks hides the staging drain. Three
//  pipelined 256^2 variants (r1-r3, r5) all regressed to ~100us/20% MfmaUtil;
//  this structure is the session's verified best. Round 7: 5 blocks/CU —
//  LDS 160 KiB/CU = exactly 5 x 32 KiB; VGPR 56 -> no allocator pressure.)
// LDS tile 128 rows x 64 shorts; XOR swizzle: row r's logical 16B chunk c at
// physical c ^ (r&7) -> conflict-free ds_read_b128, lane-contiguous staging.
__device__ __forceinline__ void gemm_core(
    const unsigned short* __restrict__ A, const unsigned short* __restrict__ B,
    int lda, int ldb, int K,
    unsigned short* ldsA, unsigned short* ldsB, f32x4 acc[4][4])
{
  const int tid  = threadIdx.x;
  const int wave = tid >> 6;
  const int lane = tid & 63;
  const int wm = (wave >> 1) * 64;
  const int wn = (wave & 1) * 64;
  const int lrow = lane & 15;
  const int kq = lane >> 4;

  // staging: wave w fills rows [w*32, w*32+32); lane covers row w*32+i*8+(lane>>3),
  // swizzled chunk (lane&7)^((lane>>3)&7); 4 calls per operand per K-chunk.
  const int sr = lane >> 3;                       // 0..7
  const int sc = (lane & 7) ^ (sr & 7);           // swizzled source chunk
  const unsigned short* ga = A + (long)(wave * 32 + sr) * lda + sc * 8;
  const unsigned short* gb = B + (long)(wave * 32 + sr) * ldb + sc * 8;
  unsigned short* lA = ldsA + wave * 2048;        // 4 KB slice per wave
  unsigned short* lB = ldsB + wave * 2048;

  const int pc0 = ((0 * 4 + kq) ^ (lrow & 7)) * 8;   // k-step 0 read chunk
  const int pc1 = ((1 * 4 + kq) ^ (lrow & 7)) * 8;   // k-step 1 read chunk

#pragma unroll 1
  for (int kb = 0; kb < K; kb += 64) {
    __syncthreads();  // previous tile fully consumed
#pragma unroll
    for (int i = 0; i < 4; ++i) {
      gload16(ga + kb + (long)i * 8 * lda, lA + i * 512);
      gload16(gb + kb + (long)i * 8 * ldb, lB + i * 512);
    }
    __syncthreads();  // drains vmcnt -> LDS valid

    bf16x8 af[4], bfr[4];
    // k-step 0 (k = kb .. kb+31)
#pragma unroll
    for (int i = 0; i < 4; ++i)
      af[i] = *(const bf16x8*)(ldsA + (wm + i * 16 + lrow) * 64 + pc0);
#pragma unroll
    for (int j = 0; j < 4; ++j)
      bfr[j] = *(const bf16x8*)(ldsB + (wn + j * 16 + lrow) * 64 + pc0);
#pragma unroll
    for (int i = 0; i < 4; ++i)
#pragma unroll
      for (int j = 0; j < 4; ++j)
        acc[i][j] = __builtin_amdgcn_mfma_f32_16x16x32_bf16(af[i], bfr[j], acc[i][j], 0, 0, 0);

    // k-step 1 (k = kb+32 .. kb+63)
#pragma unroll
    for (int i = 0; i < 4; ++i)
      af[i] = *(const bf16x8*)(ldsA + (wm + i * 16 + lrow) * 64 + pc1);
#pragma unroll
    for (int j = 0; j < 4; ++j)
      bfr[j] = *(const bf16x8*)(ldsB + (wn + j * 16 + lrow) * 64 + pc1);
#pragma unroll
    for (int i = 0; i < 4; ++i)
#pragma unroll
      for (int j = 0; j < 4; ++j)
        acc[i][j] = __builtin_amdgcn_mfma_f32_16x16x32_bf16(af[i], bfr[j], acc[i][j], 0, 0, 0);
  }
}

// QKV projection: x[8192,1024] * W[1024,1024]^T + b, fused over Q/K/V via blockIdx.y.
// Q,K stored row-major bf16; V stored transposed per batch: Vt[b][d][m].
__global__ __launch_bounds__(256, 5) void gemm_qkv(
    const unsigned short* __restrict__ xh,
    const unsigned short* __restrict__ wh,
    const float* __restrict__ bq, const float* __restrict__ bk, const float* __restrict__ bv,
    unsigned short* __restrict__ Qh, unsigned short* __restrict__ Kh,
    unsigned short* __restrict__ Vth)
{
  __shared__ __align__(16) unsigned short ldsA[8192];
  __shared__ __align__(16) unsigned short ldsB[8192];
  const int Mblk = blockIdx.x * 128;
  const int sel  = blockIdx.y >> 3;   // 0=Q 1=K 2=V
  const int nb   = blockIdx.y & 7;    // 128-wide col block within 1024

  const unsigned short* A = xh + (long)Mblk * 1024;
  const unsigned short* B = wh + sel * 1048576 + (long)(nb * 128) * 1024;
  const float* bias = (sel == 0) ? bq : (sel == 1) ? bk : bv;

  f32x4 acc[4][4] = {};
  gemm_core(A, B, 1024, 1024, 1024, ldsA, ldsB, acc);

  const int lane = threadIdx.x & 63, wave = threadIdx.x >> 6;
  const int wm = (wave >> 1) * 64, wn = (wave & 1) * 64;
  const int lrow = lane & 15, kq = lane >> 4;

#pragma unroll
  for (int i = 0; i < 4; ++i) {
#pragma unroll
    for (int j = 0; j < 4; ++j) {
      const int col = nb * 128 + wn + j * 16 + lrow;   // output feature d
      const float bsv = bias[col];
#pragma unroll
      for (int r = 0; r < 4; ++r) {
        const int tok = Mblk + wm + i * 16 + kq * 4 + r;  // token index
        const unsigned short h = f2bf(acc[i][j][r] + bsv);
        if (sel == 2) {
          Vth[(long)(tok >> 11) * 2097152 + (long)col * 2048 + (tok & 2047)] = h;
        } else if (sel == 0) {
          Qh[(long)tok * 1024 + col] = h;
        } else {
          Kh[(long)tok * 1024 + col] = h;
        }
      }
    }
  }
}

// Batched NT GEMM with fp32 output: C[z] = alpha * A[z] * B[z]^T
__global__ __launch_bounds__(256, 5) void gemm_f32out(
    const unsigned short* __restrict__ A, const unsigned short* __restrict__ B,
    int lda, int ldb, int K,
    long sA, long sB, float* __restrict__ C, int ldc, long sC, float alpha)
{
  __shared__ __align__(16) unsigned short ldsA[8192];
  __shared__ __align__(16) unsigned short ldsB[8192];
  const int Mblk = blockIdx.x * 128;
  const int Nblk = blockIdx.y * 128;
  const long z = blockIdx.z;
  const unsigned short* Ab = A + z * sA + (long)Mblk * lda;
  const unsigned short* Bb = B + z * sB + (long)Nblk * ldb;
  float* Cb = C + z * sC;

  f32x4 acc[4][4] = {};
  gemm_core(Ab, Bb, lda, ldb, K, ldsA, ldsB, acc);

  const int lane = threadIdx.x & 63, wave = threadIdx.x >> 6;
  const int wm = (wave >> 1) * 64, wn = (wave & 1) * 64;
  const int lrow = lane & 15, kq = lane >> 4;
#pragma unroll
  for (int i = 0; i < 4; ++i)
#pragma unroll
    for (int j = 0; j < 4; ++j)
#pragma unroll
      for (int r = 0; r < 4; ++r) {
        const int row = Mblk + wm + i * 16 + kq * 4 + r;
        const int col = Nblk + wn + j * 16 + lrow;
        Cb[(long)row * ldc + col] = alpha * acc[i][j][r];
      }
}

// Row softmax over 2048 entries, in place (fp32) + bf16 copy for the PV GEMM.
__global__ __launch_bounds__(256) void softmax_rows(
    float* __restrict__ S, unsigned short* __restrict__ Ph)
{
  __shared__ float red[4];
  const long row = blockIdx.x;
  float* rp = S + row * 2048;
  const int t = threadIdx.x;

  float x[8];
  *(float4*)&x[0] = reinterpret_cast<const float4*>(rp)[t];
  *(float4*)&x[4] = reinterpret_cast<const float4*>(rp)[t + 256];

  float m = x[0];
#pragma unroll
  for (int i = 1; i < 8; ++i) m = fmaxf(m, x[i]);
  for (int o = 32; o; o >>= 1) m = fmaxf(m, __shfl_xor(m, o, 64));
  if ((t & 63) == 0) red[t >> 6] = m;
  __syncthreads();
  m = fmaxf(fmaxf(red[0], red[1]), fmaxf(red[2], red[3]));
  __syncthreads();

  float s = 0.f;
#pragma unroll
  for (int i = 0; i < 8; ++i) { x[i] = __expf(x[i] - m); s += x[i]; }
  for (int o = 32; o; o >>= 1) s += __shfl_xor(s, o, 64);
  if ((t & 63) == 0) red[t >> 6] = s;
  __syncthreads();
  s = (red[0] + red[1]) + (red[2] + red[3]);
  const float inv = 1.0f / s;

#pragma unroll
  for (int i = 0; i < 8; ++i) x[i] *= inv;
  reinterpret_cast<float4*>(rp)[t]       = *(float4*)&x[0];
  reinterpret_cast<float4*>(rp)[t + 256] = *(float4*)&x[4];

  // packed bf16 P stores (2 x 8B instead of 8 x 2B)
  ushort4 p0, p1;
  p0.x = f2bf(x[0]); p0.y = f2bf(x[1]); p0.z = f2bf(x[2]); p0.w = f2bf(x[3]);
  p1.x = f2bf(x[4]); p1.y = f2bf(x[5]); p1.z = f2bf(x[6]); p1.w = f2bf(x[7]);
  const long b0 = row * 2048 + t * 4;
  *reinterpret_cast<ushort4*>(Ph + b0)        = p0;
  *reinterpret_cast<ushort4*>(Ph + b0 + 1024) = p1;
}

// One fused cast pass: x (2,097,152 float4) then Wq|Wk|Wv (262,144 float4 each).
__global__ __launch_bounds__(256) void to_bf16_all(
    const float* __restrict__ x,
    const float* __restrict__ Wq, const float* __restrict__ Wk,
    const float* __restrict__ Wv,
    unsigned short* __restrict__ xh, unsigned short* __restrict__ wh)
{
  const int stride = gridDim.x * 256;
  for (int i = blockIdx.x * 256 + threadIdx.x; i < 2883584; i += stride) {
    const float* src; unsigned short* dst; int off;
    if (i < 2097152)      { src = x;  dst = xh; off = i; }
    else {
      const int j = i - 2097152;
      const int sel = j >> 18;          // 0..2 (262144 float4 per W)
      off = j & 262143;
      src = (sel == 0) ? Wq : (sel == 1) ? Wk : Wv;
      dst = wh + (long)sel * 1048576;
    }
    const float4 v = reinterpret_cast<const float4*>(src)[off];
    ushort4 h;
    h.x = f2bf(v.x); h.y = f2bf(v.y); h.z = f2bf(v.z); h.w = f2bf(v.w);
    reinterpret_cast<ushort4*>(dst)[off] = h;
  }
}

extern "C" void kernel_launch(void* const* d_in, const int* in_sizes, int n_in,
                              void* d_out, int out_size, void* d_ws, size_t ws_size,
                              hipStream_t stream)
{
  const float* x  = (const float*)d_in[0];
  const float* Wq = (const float*)d_in[1];
  const float* bq = (const float*)d_in[2];
  const float* Wk = (const float*)d_in[3];
  const float* bk = (const float*)d_in[4];
  const float* Wv = (const float*)d_in[5];
  const float* bv = (const float*)d_in[6];

  float* out  = (float*)d_out;                 // [4,2048,1024]
  float* attn = (float*)d_out + 8388608;       // [4,2048,2048]

  unsigned short* ws  = (unsigned short*)d_ws;
  unsigned short* xh  = ws;                    //  8,388,608
  unsigned short* wh  = xh + 8388608;          //  3,145,728 (Wq|Wk|Wv)
  unsigned short* Qh  = wh + 3145728;          //  8,388,608
  unsigned short* Kh  = Qh + 8388608;          //  8,388,608
  unsigned short* Vth = Kh + 8388608;          //  8,388,608  Vt[b][d][m]
  unsigned short* Ph  = Vth + 8388608;         // 16,777,216  P bf16

  to_bf16_all<<<2048, 256, 0, stream>>>(x, Wq, Wk, Wv, xh, wh);

  // Q,K,V projections (M=8192, N=3x1024, K=1024)
  gemm_qkv<<<dim3(64, 24), 256, 0, stream>>>(xh, wh, bq, bk, bv, Qh, Kh, Vth);

  // scores = Q K^T / 32  -> fp32 straight into d_out's attention slot
  gemm_f32out<<<dim3(16, 16, 4), 256, 0, stream>>>(Qh, Kh, 1024, 1024, 1024,
      2097152L, 2097152L, attn, 2048, 4194304L, 0.03125f);

  // softmax rows in place + emit P bf16
  softmax_rows<<<8192, 256, 0, stream>>>(attn, Ph);

  // out = P * Vt^T
  gemm_f32out<<<dim3(16, 8, 4), 256, 0, stream>>>(Ph, Vth, 2048, 2048, 2048,
      4194304L, 2097152L, out, 1024, 2097152L, 1.0f);
}

// Round 9
// 303.163 us; speedup vs baseline: 1.3242x; 1.3242x over previous
//
#include <hip/hip_runtime.h>
#include <cstdint>

typedef __attribute__((ext_vector_type(8))) short bf16x8;
typedef __attribute__((ext_vector_type(4))) float f32x4;

__device__ __forceinline__ unsigned short f2bf(float v) {
  unsigned u = __builtin_bit_cast(unsigned, v);
  u += 0x7FFFu + ((u >> 16) & 1u);   // RNE
  return (unsigned short)(u >> 16);
}

// async global->LDS, 16B per lane; LDS dest = wave-uniform base + lane*16
__device__ __forceinline__ void gload16(const unsigned short* g, unsigned short* l) {
  __builtin_amdgcn_global_load_lds(
      (const __attribute__((address_space(1))) void*)(uintptr_t)g,
      (__attribute__((address_space(3))) void*)(uint32_t)(uintptr_t)l,
      16, 0, 0);
}

// Single-pass bf16 NT GEMM core: C[128x128] += A[128xK] * B[128xK]^T, BK=64.
// (r0-proven structure: 2x __syncthreads per K-tile, 256 thr / 4 waves,
//  32 KiB LDS -> TLP from 4 co-resident blocks hides the staging drain.
//  Session evidence: three pipelined 256^2 variants (r1-r3, r5) all regressed
//  to ~100us/20% MfmaUtil; launch_bounds(256,5) (r7) forced VGPR 56->48 and
//  spilled (200us dispatch, 256MB scratch writes). (256,4) + this core is
//  the verified best — do not touch.)
// LDS tile 128 rows x 64 shorts; XOR swizzle: row r's logical 16B chunk c at
// physical c ^ (r&7) -> conflict-free ds_read_b128, lane-contiguous staging.
__device__ __forceinline__ void gemm_core(
    const unsigned short* __restrict__ A, const unsigned short* __restrict__ B,
    int lda, int ldb, int K,
    unsigned short* ldsA, unsigned short* ldsB, f32x4 acc[4][4])
{
  const int tid  = threadIdx.x;
  const int wave = tid >> 6;
  const int lane = tid & 63;
  const int wm = (wave >> 1) * 64;
  const int wn = (wave & 1) * 64;
  const int lrow = lane & 15;
  const int kq = lane >> 4;

  // staging: wave w fills rows [w*32, w*32+32); lane covers row w*32+i*8+(lane>>3),
  // swizzled chunk (lane&7)^((lane>>3)&7); 4 calls per operand per K-chunk.
  const int sr = lane >> 3;                       // 0..7
  const int sc = (lane & 7) ^ (sr & 7);           // swizzled source chunk
  const unsigned short* ga = A + (long)(wave * 32 + sr) * lda + sc * 8;
  const unsigned short* gb = B + (long)(wave * 32 + sr) * ldb + sc * 8;
  unsigned short* lA = ldsA + wave * 2048;        // 4 KB slice per wave
  unsigned short* lB = ldsB + wave * 2048;

  const int pc0 = ((0 * 4 + kq) ^ (lrow & 7)) * 8;   // k-step 0 read chunk
  const int pc1 = ((1 * 4 + kq) ^ (lrow & 7)) * 8;   // k-step 1 read chunk

#pragma unroll 1
  for (int kb = 0; kb < K; kb += 64) {
    __syncthreads();  // previous tile fully consumed
#pragma unroll
    for (int i = 0; i < 4; ++i) {
      gload16(ga + kb + (long)i * 8 * lda, lA + i * 512);
      gload16(gb + kb + (long)i * 8 * ldb, lB + i * 512);
    }
    __syncthreads();  // drains vmcnt -> LDS valid

    bf16x8 af[4], bfr[4];
    // k-step 0 (k = kb .. kb+31)
#pragma unroll
    for (int i = 0; i < 4; ++i)
      af[i] = *(const bf16x8*)(ldsA + (wm + i * 16 + lrow) * 64 + pc0);
#pragma unroll
    for (int j = 0; j < 4; ++j)
      bfr[j] = *(const bf16x8*)(ldsB + (wn + j * 16 + lrow) * 64 + pc0);
#pragma unroll
    for (int i = 0; i < 4; ++i)
#pragma unroll
      for (int j = 0; j < 4; ++j)
        acc[i][j] = __builtin_amdgcn_mfma_f32_16x16x32_bf16(af[i], bfr[j], acc[i][j], 0, 0, 0);

    // k-step 1 (k = kb+32 .. kb+63)
#pragma unroll
    for (int i = 0; i < 4; ++i)
      af[i] = *(const bf16x8*)(ldsA + (wm + i * 16 + lrow) * 64 + pc1);
#pragma unroll
    for (int j = 0; j < 4; ++j)
      bfr[j] = *(const bf16x8*)(ldsB + (wn + j * 16 + lrow) * 64 + pc1);
#pragma unroll
    for (int i = 0; i < 4; ++i)
#pragma unroll
      for (int j = 0; j < 4; ++j)
        acc[i][j] = __builtin_amdgcn_mfma_f32_16x16x32_bf16(af[i], bfr[j], acc[i][j], 0, 0, 0);
  }
}

// QKV projection: x[8192,1024] * W[1024,1024]^T + b, fused over Q/K/V via blockIdx.y.
// Q,K stored row-major bf16; V stored transposed per batch: Vt[b][d][m].
__global__ __launch_bounds__(256, 4) void gemm_qkv(
    const unsigned short* __restrict__ xh,
    const unsigned short* __restrict__ wh,
    const float* __restrict__ bq, const float* __restrict__ bk, const float* __restrict__ bv,
    unsigned short* __restrict__ Qh, unsigned short* __restrict__ Kh,
    unsigned short* __restrict__ Vth)
{
  __shared__ __align__(16) unsigned short ldsA[8192];
  __shared__ __align__(16) unsigned short ldsB[8192];
  const int Mblk = blockIdx.x * 128;
  const int sel  = blockIdx.y >> 3;   // 0=Q 1=K 2=V
  const int nb   = blockIdx.y & 7;    // 128-wide col block within 1024

  const unsigned short* A = xh + (long)Mblk * 1024;
  const unsigned short* B = wh + sel * 1048576 + (long)(nb * 128) * 1024;
  const float* bias = (sel == 0) ? bq : (sel == 1) ? bk : bv;

  f32x4 acc[4][4] = {};
  gemm_core(A, B, 1024, 1024, 1024, ldsA, ldsB, acc);

  const int lane = threadIdx.x & 63, wave = threadIdx.x >> 6;
  const int wm = (wave >> 1) * 64, wn = (wave & 1) * 64;
  const int lrow = lane & 15, kq = lane >> 4;

#pragma unroll
  for (int i = 0; i < 4; ++i) {
#pragma unroll
    for (int j = 0; j < 4; ++j) {
      const int col = nb * 128 + wn + j * 16 + lrow;   // output feature d
      const float bsv = bias[col];
#pragma unroll
      for (int r = 0; r < 4; ++r) {
        const int tok = Mblk + wm + i * 16 + kq * 4 + r;  // token index
        const unsigned short h = f2bf(acc[i][j][r] + bsv);
        if (sel == 2) {
          Vth[(long)(tok >> 11) * 2097152 + (long)col * 2048 + (tok & 2047)] = h;
        } else if (sel == 0) {
          Qh[(long)tok * 1024 + col] = h;
        } else {
          Kh[(long)tok * 1024 + col] = h;
        }
      }
    }
  }
}

// Batched NT GEMM with fp32 output: C[z] = alpha * A[z] * B[z]^T.
// ntout: nontemporal C stores (final outputs that are never re-read on-device).
__global__ __launch_bounds__(256, 4) void gemm_f32out(
    const unsigned short* __restrict__ A, const unsigned short* __restrict__ B,
    int lda, int ldb, int K,
    long sA, long sB, float* __restrict__ C, int ldc, long sC, float alpha,
    int ntout)
{
  __shared__ __align__(16) unsigned short ldsA[8192];
  __shared__ __align__(16) unsigned short ldsB[8192];
  const int Mblk = blockIdx.x * 128;
  const int Nblk = blockIdx.y * 128;
  const long z = blockIdx.z;
  const unsigned short* Ab = A + z * sA + (long)Mblk * lda;
  const unsigned short* Bb = B + z * sB + (long)Nblk * ldb;
  float* Cb = C + z * sC;

  f32x4 acc[4][4] = {};
  gemm_core(Ab, Bb, lda, ldb, K, ldsA, ldsB, acc);

  const int lane = threadIdx.x & 63, wave = threadIdx.x >> 6;
  const int wm = (wave >> 1) * 64, wn = (wave & 1) * 64;
  const int lrow = lane & 15, kq = lane >> 4;
#pragma unroll
  for (int i = 0; i < 4; ++i)
#pragma unroll
    for (int j = 0; j < 4; ++j)
#pragma unroll
      for (int r = 0; r < 4; ++r) {
        const int row = Mblk + wm + i * 16 + kq * 4 + r;
        const int col = Nblk + wn + j * 16 + lrow;
        float* p = Cb + (long)row * ldc + col;
        const float v = alpha * acc[i][j][r];
        if (ntout) __builtin_nontemporal_store(v, p);
        else       *p = v;
      }
}

// Row softmax over 2048 entries, in place (fp32) + bf16 copy for the PV GEMM.
// attn (fp32, normalized) is a final output never re-read on-device -> NT
// stores keep it from evicting P/Vt from L2/LLC before the PV GEMM runs.
__global__ __launch_bounds__(256) void softmax_rows(
    float* __restrict__ S, unsigned short* __restrict__ Ph)
{
  __shared__ float red[4];
  const long row = blockIdx.x;
  float* rp = S + row * 2048;
  const int t = threadIdx.x;

  float x[8];
  *(float4*)&x[0] = reinterpret_cast<const float4*>(rp)[t];
  *(float4*)&x[4] = reinterpret_cast<const float4*>(rp)[t + 256];

  float m = x[0];
#pragma unroll
  for (int i = 1; i < 8; ++i) m = fmaxf(m, x[i]);
  for (int o = 32; o; o >>= 1) m = fmaxf(m, __shfl_xor(m, o, 64));
  if ((t & 63) == 0) red[t >> 6] = m;
  __syncthreads();
  m = fmaxf(fmaxf(red[0], red[1]), fmaxf(red[2], red[3]));
  __syncthreads();

  float s = 0.f;
#pragma unroll
  for (int i = 0; i < 8; ++i) { x[i] = __expf(x[i] - m); s += x[i]; }
  for (int o = 32; o; o >>= 1) s += __shfl_xor(s, o, 64);
  if ((t & 63) == 0) red[t >> 6] = s;
  __syncthreads();
  s = (red[0] + red[1]) + (red[2] + red[3]);
  const float inv = 1.0f / s;

#pragma unroll
  for (int i = 0; i < 8; ++i) x[i] *= inv;
  // NT stores via clang ext_vector f32x4 (HIP float4 is a class type and is
  // rejected by __builtin_nontemporal_store)
  __builtin_nontemporal_store(*(const f32x4*)&x[0],
                              reinterpret_cast<f32x4*>(rp) + t);
  __builtin_nontemporal_store(*(const f32x4*)&x[4],
                              reinterpret_cast<f32x4*>(rp) + t + 256);

  // packed bf16 P stores (2 x 8B instead of 8 x 2B); P is re-read by PV -> cached
  ushort4 p0, p1;
  p0.x = f2bf(x[0]); p0.y = f2bf(x[1]); p0.z = f2bf(x[2]); p0.w = f2bf(x[3]);
  p1.x = f2bf(x[4]); p1.y = f2bf(x[5]); p1.z = f2bf(x[6]); p1.w = f2bf(x[7]);
  const long b0 = row * 2048 + t * 4;
  *reinterpret_cast<ushort4*>(Ph + b0)        = p0;
  *reinterpret_cast<ushort4*>(Ph + b0 + 1024) = p1;
}

// One fused cast pass: x (2,097,152 float4) then Wq|Wk|Wv (262,144 float4 each).
__global__ __launch_bounds__(256) void to_bf16_all(
    const float* __restrict__ x,
    const float* __restrict__ Wq, const float* __restrict__ Wk,
    const float* __restrict__ Wv,
    unsigned short* __restrict__ xh, unsigned short* __restrict__ wh)
{
  const int stride = gridDim.x * 256;
  for (int i = blockIdx.x * 256 + threadIdx.x; i < 2883584; i += stride) {
    const float* src; unsigned short* dst; int off;
    if (i < 2097152)      { src = x;  dst = xh; off = i; }
    else {
      const int j = i - 2097152;
      const int sel = j >> 18;          // 0..2 (262144 float4 per W)
      off = j & 262143;
      src = (sel == 0) ? Wq : (sel == 1) ? Wk : Wv;
      dst = wh + (long)sel * 1048576;
    }
    const float4 v = reinterpret_cast<const float4*>(src)[off];
    ushort4 h;
    h.x = f2bf(v.x); h.y = f2bf(v.y); h.z = f2bf(v.z); h.w = f2bf(v.w);
    reinterpret_cast<ushort4*>(dst)[off] = h;
  }
}

extern "C" void kernel_launch(void* const* d_in, const int* in_sizes, int n_in,
                              void* d_out, int out_size, void* d_ws, size_t ws_size,
                              hipStream_t stream)
{
  const float* x  = (const float*)d_in[0];
  const float* Wq = (const float*)d_in[1];
  const float* bq = (const float*)d_in[2];
  const float* Wk = (const float*)d_in[3];
  const float* bk = (const float*)d_in[4];
  const float* Wv = (const float*)d_in[5];
  const float* bv = (const float*)d_in[6];

  float* out  = (float*)d_out;                 // [4,2048,1024]
  float* attn = (float*)d_out + 8388608;       // [4,2048,2048]

  unsigned short* ws  = (unsigned short*)d_ws;
  unsigned short* xh  = ws;                    //  8,388,608
  unsigned short* wh  = xh + 8388608;          //  3,145,728 (Wq|Wk|Wv)
  unsigned short* Qh  = wh + 3145728;          //  8,388,608
  unsigned short* Kh  = Qh + 8388608;          //  8,388,608
  unsigned short* Vth = Kh + 8388608;          //  8,388,608  Vt[b][d][m]
  unsigned short* Ph  = Vth + 8388608;         // 16,777,216  P bf16

  to_bf16_all<<<2048, 256, 0, stream>>>(x, Wq, Wk, Wv, xh, wh);

  // Q,K,V projections (M=8192, N=3x1024, K=1024)
  gemm_qkv<<<dim3(64, 24), 256, 0, stream>>>(xh, wh, bq, bk, bv, Qh, Kh, Vth);

  // scores = Q K^T / 32 -> fp32 S (re-read by softmax: cached stores)
  gemm_f32out<<<dim3(16, 16, 4), 256, 0, stream>>>(Qh, Kh, 1024, 1024, 1024,
      2097152L, 2097152L, attn, 2048, 4194304L, 0.03125f, 0);

  // softmax rows in place (NT attn stores) + emit P bf16
  softmax_rows<<<8192, 256, 0, stream>>>(attn, Ph);

  // out = P * Vt^T (final output: NT stores)
  gemm_f32out<<<dim3(16, 8, 4), 256, 0, stream>>>(Ph, Vth, 2048, 2048, 2048,
      4194304L, 2097152L, out, 1024, 2097152L, 1.0f, 1);
}

// Round 10
// 300.982 us; speedup vs baseline: 1.3338x; 1.0072x over previous
//
#include <hip/hip_runtime.h>
#include <cstdint>

typedef __attribute__((ext_vector_type(8))) short bf16x8;
typedef __attribute__((ext_vector_type(4))) float f32x4;

__device__ __forceinline__ unsigned short f2bf(float v) {
  unsigned u = __builtin_bit_cast(unsigned, v);
  u += 0x7FFFu + ((u >> 16) & 1u);   // RNE
  return (unsigned short)(u >> 16);
}

// async global->LDS, 16B per lane; LDS dest = wave-uniform base + lane*16
__device__ __forceinline__ void gload16(const unsigned short* g, unsigned short* l) {
  __builtin_amdgcn_global_load_lds(
      (const __attribute__((address_space(1))) void*)(uintptr_t)g,
      (__attribute__((address_space(3))) void*)(uint32_t)(uintptr_t)l,
      16, 0, 0);
}

// Single-pass bf16 NT GEMM core: C[128x128] += A[128xK] * B[128xK]^T, BK=64.
// (r0-proven structure: 2x __syncthreads per K-tile, 256 thr / 4 waves,
//  32 KiB LDS -> TLP from 4 co-resident blocks hides the staging drain.
//  Session evidence: three pipelined 256^2 variants (r1-r3, r5) all regressed
//  to ~100us/20% MfmaUtil; launch_bounds(256,5) (r7) forced VGPR 56->48 and
//  spilled (200us dispatch, 256MB scratch writes). (256,4) + this core is
//  the verified best — do not touch.)
// LDS tile 128 rows x 64 shorts; XOR swizzle: row r's logical 16B chunk c at
// physical c ^ (r&7) -> conflict-free ds_read_b128, lane-contiguous staging.
__device__ __forceinline__ void gemm_core(
    const unsigned short* __restrict__ A, const unsigned short* __restrict__ B,
    int lda, int ldb, int K,
    unsigned short* ldsA, unsigned short* ldsB, f32x4 acc[4][4])
{
  const int tid  = threadIdx.x;
  const int wave = tid >> 6;
  const int lane = tid & 63;
  const int wm = (wave >> 1) * 64;
  const int wn = (wave & 1) * 64;
  const int lrow = lane & 15;
  const int kq = lane >> 4;

  // staging: wave w fills rows [w*32, w*32+32); lane covers row w*32+i*8+(lane>>3),
  // swizzled chunk (lane&7)^((lane>>3)&7); 4 calls per operand per K-chunk.
  const int sr = lane >> 3;                       // 0..7
  const int sc = (lane & 7) ^ (sr & 7);           // swizzled source chunk
  const unsigned short* ga = A + (long)(wave * 32 + sr) * lda + sc * 8;
  const unsigned short* gb = B + (long)(wave * 32 + sr) * ldb + sc * 8;
  unsigned short* lA = ldsA + wave * 2048;        // 4 KB slice per wave
  unsigned short* lB = ldsB + wave * 2048;

  const int pc0 = ((0 * 4 + kq) ^ (lrow & 7)) * 8;   // k-step 0 read chunk
  const int pc1 = ((1 * 4 + kq) ^ (lrow & 7)) * 8;   // k-step 1 read chunk

#pragma unroll 1
  for (int kb = 0; kb < K; kb += 64) {
    __syncthreads();  // previous tile fully consumed
#pragma unroll
    for (int i = 0; i < 4; ++i) {
      gload16(ga + kb + (long)i * 8 * lda, lA + i * 512);
      gload16(gb + kb + (long)i * 8 * ldb, lB + i * 512);
    }
    __syncthreads();  // drains vmcnt -> LDS valid

    bf16x8 af[4], bfr[4];
    // k-step 0 (k = kb .. kb+31)
#pragma unroll
    for (int i = 0; i < 4; ++i)
      af[i] = *(const bf16x8*)(ldsA + (wm + i * 16 + lrow) * 64 + pc0);
#pragma unroll
    for (int j = 0; j < 4; ++j)
      bfr[j] = *(const bf16x8*)(ldsB + (wn + j * 16 + lrow) * 64 + pc0);
#pragma unroll
    for (int i = 0; i < 4; ++i)
#pragma unroll
      for (int j = 0; j < 4; ++j)
        acc[i][j] = __builtin_amdgcn_mfma_f32_16x16x32_bf16(af[i], bfr[j], acc[i][j], 0, 0, 0);

    // k-step 1 (k = kb+32 .. kb+63)
#pragma unroll
    for (int i = 0; i < 4; ++i)
      af[i] = *(const bf16x8*)(ldsA + (wm + i * 16 + lrow) * 64 + pc1);
#pragma unroll
    for (int j = 0; j < 4; ++j)
      bfr[j] = *(const bf16x8*)(ldsB + (wn + j * 16 + lrow) * 64 + pc1);
#pragma unroll
    for (int i = 0; i < 4; ++i)
#pragma unroll
      for (int j = 0; j < 4; ++j)
        acc[i][j] = __builtin_amdgcn_mfma_f32_16x16x32_bf16(af[i], bfr[j], acc[i][j], 0, 0, 0);
  }
}

// QKV projection: x[8192,1024] * W[1024,1024]^T + b, fused over Q/K/V via blockIdx.y.
// Q,K stored row-major bf16; V stored transposed per batch: Vt[b][d][m].
__global__ __launch_bounds__(256, 4) void gemm_qkv(
    const unsigned short* __restrict__ xh,
    const unsigned short* __restrict__ wh,
    const float* __restrict__ bq, const float* __restrict__ bk, const float* __restrict__ bv,
    unsigned short* __restrict__ Qh, unsigned short* __restrict__ Kh,
    unsigned short* __restrict__ Vth)
{
  __shared__ __align__(16) unsigned short ldsA[8192];
  __shared__ __align__(16) unsigned short ldsB[8192];
  const int Mblk = blockIdx.x * 128;
  const int sel  = blockIdx.y >> 3;   // 0=Q 1=K 2=V
  const int nb   = blockIdx.y & 7;    // 128-wide col block within 1024

  const unsigned short* A = xh + (long)Mblk * 1024;
  const unsigned short* B = wh + sel * 1048576 + (long)(nb * 128) * 1024;
  const float* bias = (sel == 0) ? bq : (sel == 1) ? bk : bv;

  f32x4 acc[4][4] = {};
  gemm_core(A, B, 1024, 1024, 1024, ldsA, ldsB, acc);

  const int lane = threadIdx.x & 63, wave = threadIdx.x >> 6;
  const int wm = (wave >> 1) * 64, wn = (wave & 1) * 64;
  const int lrow = lane & 15, kq = lane >> 4;

#pragma unroll
  for (int i = 0; i < 4; ++i) {
#pragma unroll
    for (int j = 0; j < 4; ++j) {
      const int col = nb * 128 + wn + j * 16 + lrow;   // output feature d
      const float bsv = bias[col];
#pragma unroll
      for (int r = 0; r < 4; ++r) {
        const int tok = Mblk + wm + i * 16 + kq * 4 + r;  // token index
        const unsigned short h = f2bf(acc[i][j][r] + bsv);
        if (sel == 2) {
          Vth[(long)(tok >> 11) * 2097152 + (long)col * 2048 + (tok & 2047)] = h;
        } else if (sel == 0) {
          Qh[(long)tok * 1024 + col] = h;
        } else {
          Kh[(long)tok * 1024 + col] = h;
        }
      }
    }
  }
}

// Batched NT GEMM with fp32 output: C[z] = alpha * A[z] * B[z]^T.
// ntout: nontemporal C stores (final outputs that are never re-read on-device).
__global__ __launch_bounds__(256, 4) void gemm_f32out(
    const unsigned short* __restrict__ A, const unsigned short* __restrict__ B,
    int lda, int ldb, int K,
    long sA, long sB, float* __restrict__ C, int ldc, long sC, float alpha,
    int ntout)
{
  __shared__ __align__(16) unsigned short ldsA[8192];
  __shared__ __align__(16) unsigned short ldsB[8192];
  const int Mblk = blockIdx.x * 128;
  const int Nblk = blockIdx.y * 128;
  const long z = blockIdx.z;
  const unsigned short* Ab = A + z * sA + (long)Mblk * lda;
  const unsigned short* Bb = B + z * sB + (long)Nblk * ldb;
  float* Cb = C + z * sC;

  f32x4 acc[4][4] = {};
  gemm_core(Ab, Bb, lda, ldb, K, ldsA, ldsB, acc);

  const int lane = threadIdx.x & 63, wave = threadIdx.x >> 6;
  const int wm = (wave >> 1) * 64, wn = (wave & 1) * 64;
  const int lrow = lane & 15, kq = lane >> 4;
#pragma unroll
  for (int i = 0; i < 4; ++i)
#pragma unroll
    for (int j = 0; j < 4; ++j)
#pragma unroll
      for (int r = 0; r < 4; ++r) {
        const int row = Mblk + wm + i * 16 + kq * 4 + r;
        const int col = Nblk + wn + j * 16 + lrow;
        float* p = Cb + (long)row * ldc + col;
        const float v = alpha * acc[i][j][r];
        if (ntout) __builtin_nontemporal_store(v, p);
        else       *p = v;
      }
}

// Row softmax over 2048 entries, in place (fp32) + bf16 copy for the PV GEMM.
// ONE WAVE PER ROW: 4 rows per 256-thr block, no LDS, no __syncthreads.
// Lane holds 32 floats (8 x f32x4 at stride-64 float4s, fully coalesced);
// reductions are 6-step __shfl_xor within the wave. Pure streaming kernel.
__global__ __launch_bounds__(256) void softmax_rows(
    float* __restrict__ S, unsigned short* __restrict__ Ph)
{
  const int wave = threadIdx.x >> 6;
  const int lane = threadIdx.x & 63;
  const long row = (long)blockIdx.x * 4 + wave;
  float* rp = S + row * 2048;
  f32x4* rv = reinterpret_cast<f32x4*>(rp);

  f32x4 x[8];
#pragma unroll
  for (int k = 0; k < 8; ++k) x[k] = rv[lane + 64 * k];

  float m = x[0][0];
#pragma unroll
  for (int k = 0; k < 8; ++k)
#pragma unroll
    for (int e = 0; e < 4; ++e) m = fmaxf(m, x[k][e]);
  for (int o = 32; o; o >>= 1) m = fmaxf(m, __shfl_xor(m, o, 64));

  float s = 0.f;
#pragma unroll
  for (int k = 0; k < 8; ++k)
#pragma unroll
    for (int e = 0; e < 4; ++e) { x[k][e] = __expf(x[k][e] - m); s += x[k][e]; }
  for (int o = 32; o; o >>= 1) s += __shfl_xor(s, o, 64);
  const float inv = 1.0f / s;

  const long pb = row * 2048;
#pragma unroll
  for (int k = 0; k < 8; ++k) {
    x[k] *= inv;
    rv[lane + 64 * k] = x[k];
    ushort4 p;
    p.x = f2bf(x[k][0]); p.y = f2bf(x[k][1]);
    p.z = f2bf(x[k][2]); p.w = f2bf(x[k][3]);
    *reinterpret_cast<ushort4*>(Ph + pb + (lane + 64 * k) * 4) = p;
  }
}

// One fused cast pass: x (2,097,152 float4) then Wq|Wk|Wv (262,144 float4 each).
__global__ __launch_bounds__(256) void to_bf16_all(
    const float* __restrict__ x,
    const float* __restrict__ Wq, const float* __restrict__ Wk,
    const float* __restrict__ Wv,
    unsigned short* __restrict__ xh, unsigned short* __restrict__ wh)
{
  const int stride = gridDim.x * 256;
  for (int i = blockIdx.x * 256 + threadIdx.x; i < 2883584; i += stride) {
    const float* src; unsigned short* dst; int off;
    if (i < 2097152)      { src = x;  dst = xh; off = i; }
    else {
      const int j = i - 2097152;
      const int sel = j >> 18;          // 0..2 (262144 float4 per W)
      off = j & 262143;
      src = (sel == 0) ? Wq : (sel == 1) ? Wk : Wv;
      dst = wh + (long)sel * 1048576;
    }
    const float4 v = reinterpret_cast<const float4*>(src)[off];
    ushort4 h;
    h.x = f2bf(v.x); h.y = f2bf(v.y); h.z = f2bf(v.z); h.w = f2bf(v.w);
    reinterpret_cast<ushort4*>(dst)[off] = h;
  }
}

extern "C" void kernel_launch(void* const* d_in, const int* in_sizes, int n_in,
                              void* d_out, int out_size, void* d_ws, size_t ws_size,
                              hipStream_t stream)
{
  const float* x  = (const float*)d_in[0];
  const float* Wq = (const float*)d_in[1];
  const float* bq = (const float*)d_in[2];
  const float* Wk = (const float*)d_in[3];
  const float* bk = (const float*)d_in[4];
  const float* Wv = (const float*)d_in[5];
  const float* bv = (const float*)d_in[6];

  float* out  = (float*)d_out;                 // [4,2048,1024]
  float* attn = (float*)d_out + 8388608;       // [4,2048,2048]

  unsigned short* ws  = (unsigned short*)d_ws;
  unsigned short* xh  = ws;                    //  8,388,608
  unsigned short* wh  = xh + 8388608;          //  3,145,728 (Wq|Wk|Wv)
  unsigned short* Qh  = wh + 3145728;          //  8,388,608
  unsigned short* Kh  = Qh + 8388608;          //  8,388,608
  unsigned short* Vth = Kh + 8388608;          //  8,388,608  Vt[b][d][m]
  unsigned short* Ph  = Vth + 8388608;         // 16,777,216  P bf16

  to_bf16_all<<<2048, 256, 0, stream>>>(x, Wq, Wk, Wv, xh, wh);

  // Q,K,V projections (M=8192, N=3x1024, K=1024)
  gemm_qkv<<<dim3(64, 24), 256, 0, stream>>>(xh, wh, bq, bk, bv, Qh, Kh, Vth);

  // scores = Q K^T / 32 -> fp32 S (re-read by softmax: cached stores)
  gemm_f32out<<<dim3(16, 16, 4), 256, 0, stream>>>(Qh, Kh, 1024, 1024, 1024,
      2097152L, 2097152L, attn, 2048, 4194304L, 0.03125f, 0);

  // softmax rows in place + emit P bf16 (one wave per row)
  softmax_rows<<<2048, 256, 0, stream>>>(attn, Ph);

  // out = P * Vt^T (final output: NT stores)
  gemm_f32out<<<dim3(16, 8, 4), 256, 0, stream>>>(Ph, Vth, 2048, 2048, 2048,
      4194304L, 2097152L, out, 1024, 2097152L, 1.0f, 1);
}